// Round 1
// baseline (1458.887 us; speedup 1.0000x reference)
//
#include <hip/hip_runtime.h>
#include <hip/hip_bf16.h>

#define B_ 2
#define S_ 2048
#define D_ 1024
#define N_ 16
#define H_ 64

// ---------------------------------------------------------------------------
// K1: wsum[d] = sum over 1024 rows (n,h) of W_out[n,h,d].  W_out = [1024][1024]
// grid 64 x 256 threads: block handles 16 d's, 16 row-slices of 64 rows each.
__global__ __launch_bounds__(256) void k_wsum(const float* __restrict__ Wout,
                                              float* __restrict__ wsum) {
    __shared__ float red[16][17];
    const int dd = threadIdx.x & 15, rr = threadIdx.x >> 4;
    const int d = blockIdx.x * 16 + dd;
    float s = 0.f;
    for (int r = rr * 64; r < rr * 64 + 64; ++r) s += Wout[(size_t)r * 1024 + d];
    red[rr][dd] = s;
    __syncthreads();
    if (rr == 0) {
        float t = 0.f;
#pragma unroll
        for (int k = 0; k < 16; ++k) t += red[k][dd];
        wsum[d] = t;
    }
}

// ---------------------------------------------------------------------------
// K2: QKV projection. qkv[b,n,s,j] = sum_d x[b,s,d] * W_qkv[n,d,j]
// grid (sb=32, jb=3, bn=32), block 256. Tile 64(M) x 64(N) x 32(K).
__global__ __launch_bounds__(256) void k_qkv(const float* __restrict__ x,
                                             const float* __restrict__ Wqkv,
                                             float* __restrict__ qbuf,
                                             float* __restrict__ kbuf,
                                             float* __restrict__ vbuf) {
    __shared__ float Ast[32][68];  // A tile transposed: [k][m]
    __shared__ float Bs[32][68];   // B tile: [k][n]
    const int sb = blockIdx.x, jb = blockIdx.y, bn = blockIdx.z;
    const int b = bn >> 4, n = bn & 15;
    const int t = threadIdx.x;
    const int ty = t >> 4, tx = t & 15;
    const float* A = x + (size_t)b * S_ * D_ + (size_t)(sb * 64) * D_;
    const float* W = Wqkv + (size_t)n * D_ * 192 + jb * 64;
    float acc[4][4] = {};
    for (int kk = 0; kk < D_; kk += 32) {
        // A tile 64x32: 512 float4, 2/thread, transposed scalar store
#pragma unroll
        for (int rep = 0; rep < 2; ++rep) {
            int v = t + rep * 256;
            int i = v >> 3, c4 = v & 7;
            float4 f = *(const float4*)(A + (size_t)i * D_ + kk + c4 * 4);
            Ast[c4 * 4 + 0][i] = f.x;
            Ast[c4 * 4 + 1][i] = f.y;
            Ast[c4 * 4 + 2][i] = f.z;
            Ast[c4 * 4 + 3][i] = f.w;
        }
        // B tile 32x64: 512 float4, 2/thread
#pragma unroll
        for (int rep = 0; rep < 2; ++rep) {
            int v = t + rep * 256;
            int r = v >> 4, c4 = v & 15;
            *(float4*)&Bs[r][c4 * 4] = *(const float4*)(W + (size_t)(kk + r) * 192 + c4 * 4);
        }
        __syncthreads();
#pragma unroll
        for (int k2 = 0; k2 < 32; ++k2) {
            float4 a4 = *(const float4*)&Ast[k2][ty * 4];
            float4 b4 = *(const float4*)&Bs[k2][tx * 4];
            float av[4] = {a4.x, a4.y, a4.z, a4.w};
            float bv[4] = {b4.x, b4.y, b4.z, b4.w};
#pragma unroll
            for (int ii = 0; ii < 4; ++ii)
#pragma unroll
                for (int jj = 0; jj < 4; ++jj) acc[ii][jj] += av[ii] * bv[jj];
        }
        __syncthreads();
    }
    float* dst = (jb == 0) ? qbuf : (jb == 1) ? kbuf : vbuf;
    dst += ((size_t)bn * S_ + (size_t)sb * 64) * H_;
#pragma unroll
    for (int ii = 0; ii < 4; ++ii) {
        int i = ty * 4 + ii;
        *(float4*)(dst + (size_t)i * H_ + tx * 4) =
            make_float4(acc[ii][0], acc[ii][1], acc[ii][2], acc[ii][3]);
    }
}

// ---------------------------------------------------------------------------
// K3: causal flash attention per (b,n). Tiles 64(q) x 64(k), online softmax.
// XOR swizzle (key bijective in row within 16) for the shared K/P buffer to
// avoid the 32-bank column-read conflict.
__device__ __forceinline__ int swz(int row, int h4) {
    return ((h4 ^ ((row + (row >> 2)) & 15)) << 2);
}

__global__ __launch_bounds__(256) void k_attn(const float* __restrict__ qbuf,
                                              const float* __restrict__ kbuf,
                                              const float* __restrict__ vbuf,
                                              float* __restrict__ obuf) {
    __shared__ float Qs[64][68];
    __shared__ float KP[64][64];  // K tile, then reused for P (both swizzled)
    __shared__ float Vs[64][64];
    const int qb = (int)gridDim.x - 1 - (int)blockIdx.x;  // long blocks first
    const int bn = blockIdx.y;
    const int t = threadIdx.x;
    const int g = t >> 4, c = t & 15;  // 16x16 thread grid
    const float* Q = qbuf + ((size_t)bn * S_ + (size_t)qb * 64) * H_;
    const float* K = kbuf + (size_t)bn * S_ * H_;
    const float* V = vbuf + (size_t)bn * S_ * H_;
#pragma unroll
    for (int rep = 0; rep < 4; ++rep) {
        int v = t + rep * 256;
        int i = v >> 4, h4 = v & 15;
        *(float4*)&Qs[i][h4 * 4] = *(const float4*)(Q + (size_t)i * H_ + h4 * 4);
    }
    float O[4][4] = {};
    float m[4], l[4];
#pragma unroll
    for (int ii = 0; ii < 4; ++ii) { m[ii] = -3.0e38f; l[ii] = 0.f; }

    for (int kb = 0; kb <= qb; ++kb) {
        __syncthreads();  // prior tile's PV reads done (also covers Q load)
#pragma unroll
        for (int rep = 0; rep < 4; ++rep) {
            int v = t + rep * 256;
            int j = v >> 4, h4 = v & 15;
            *(float4*)&KP[j][swz(j, h4)] =
                *(const float4*)(K + (size_t)(kb * 64 + j) * H_ + h4 * 4);
            *(float4*)&Vs[j][h4 * 4] =
                *(const float4*)(V + (size_t)(kb * 64 + j) * H_ + h4 * 4);
        }
        __syncthreads();
        // scores S[i=g*4+ii][j=c*4+jj] = q . k
        float s[4][4] = {};
#pragma unroll
        for (int h4 = 0; h4 < 16; ++h4) {
            float4 q4[4], k4[4];
#pragma unroll
            for (int ii = 0; ii < 4; ++ii) q4[ii] = *(const float4*)&Qs[g * 4 + ii][h4 * 4];
#pragma unroll
            for (int jj = 0; jj < 4; ++jj) {
                int j = c * 4 + jj;
                k4[jj] = *(const float4*)&KP[j][swz(j, h4)];
            }
#pragma unroll
            for (int ii = 0; ii < 4; ++ii) {
                float qv[4] = {q4[ii].x, q4[ii].y, q4[ii].z, q4[ii].w};
#pragma unroll
                for (int jj = 0; jj < 4; ++jj) {
                    s[ii][jj] += qv[0] * k4[jj].x + qv[1] * k4[jj].y +
                                 qv[2] * k4[jj].z + qv[3] * k4[jj].w;
                }
            }
        }
        // scale + causal mask + online softmax
        float tm[4], f_[4], ts[4];
#pragma unroll
        for (int ii = 0; ii < 4; ++ii) {
            tm[ii] = -3.0e38f;
            int qi = qb * 64 + g * 4 + ii;
#pragma unroll
            for (int jj = 0; jj < 4; ++jj) {
                int kj = kb * 64 + c * 4 + jj;
                float sv = s[ii][jj] * 0.125f;
                if (kj > qi) sv = -3.0e38f;
                s[ii][jj] = sv;
                tm[ii] = fmaxf(tm[ii], sv);
            }
        }
#pragma unroll
        for (int ii = 0; ii < 4; ++ii) {
            tm[ii] = fmaxf(tm[ii], __shfl_xor(tm[ii], 1, 16));
            tm[ii] = fmaxf(tm[ii], __shfl_xor(tm[ii], 2, 16));
            tm[ii] = fmaxf(tm[ii], __shfl_xor(tm[ii], 4, 16));
            tm[ii] = fmaxf(tm[ii], __shfl_xor(tm[ii], 8, 16));
            float mn = fmaxf(m[ii], tm[ii]);
            f_[ii] = expf(m[ii] - mn);
            m[ii] = mn;
            float sum = 0.f;
#pragma unroll
            for (int jj = 0; jj < 4; ++jj) {
                float p = expf(s[ii][jj] - mn);
                s[ii][jj] = p;
                sum += p;
            }
            ts[ii] = sum;
            ts[ii] += __shfl_xor(ts[ii], 1, 16);
            ts[ii] += __shfl_xor(ts[ii], 2, 16);
            ts[ii] += __shfl_xor(ts[ii], 4, 16);
            ts[ii] += __shfl_xor(ts[ii], 8, 16);
            l[ii] = l[ii] * f_[ii] + ts[ii];
        }
        __syncthreads();  // all K reads done before P overwrites KP
        // write P (swizzled by row i), rescale O
#pragma unroll
        for (int ii = 0; ii < 4; ++ii) {
            int i = g * 4 + ii;
#pragma unroll
            for (int jj = 0; jj < 4; ++jj) {
                KP[i][swz(i, c) + jj] = s[ii][jj];
                O[ii][jj] *= f_[ii];
            }
        }
        __syncthreads();  // P visible
        // PV: O[i][h] += sum_j P[i][j] * V[j][h]   (i=g*4+ii, h=c*4+jj)
#pragma unroll
        for (int j4 = 0; j4 < 16; ++j4) {
            float4 p4[4], v4[4];
#pragma unroll
            for (int ii = 0; ii < 4; ++ii) {
                int i = g * 4 + ii;
                p4[ii] = *(const float4*)&KP[i][swz(i, j4)];
            }
#pragma unroll
            for (int e = 0; e < 4; ++e) v4[e] = *(const float4*)&Vs[j4 * 4 + e][c * 4];
#pragma unroll
            for (int ii = 0; ii < 4; ++ii) {
                float pv[4] = {p4[ii].x, p4[ii].y, p4[ii].z, p4[ii].w};
#pragma unroll
                for (int e = 0; e < 4; ++e) {
                    O[ii][0] += pv[e] * v4[e].x;
                    O[ii][1] += pv[e] * v4[e].y;
                    O[ii][2] += pv[e] * v4[e].z;
                    O[ii][3] += pv[e] * v4[e].w;
                }
            }
        }
    }
    // normalize + store
#pragma unroll
    for (int ii = 0; ii < 4; ++ii) {
        float inv = 1.f / l[ii];
        int i = g * 4 + ii;
        *(float4*)(obuf + ((size_t)bn * S_ + (size_t)qb * 64 + i) * H_ + c * 4) =
            make_float4(O[ii][0] * inv, O[ii][1] * inv, O[ii][2] * inv, O[ii][3] * inv);
    }
}

// ---------------------------------------------------------------------------
// K4: permute + scale.  final[b, s2, 64n+r] = attn[b,n, 32r + s2/64, s2%64] * wsum[64n+r]
// grid (t=32, n=16, b=2), block 256. LDS transpose tile.
__global__ __launch_bounds__(256) void k_perm(const float* __restrict__ obuf,
                                              const float* __restrict__ wsum,
                                              float* __restrict__ out) {
    __shared__ float T[64][65];
    const int tt = blockIdx.x, n = blockIdx.y, b = blockIdx.z;
    const int tid = threadIdx.x;
    const float* src = obuf + ((size_t)(b * 16 + n) * S_) * H_;
    // T[r][h] = attn[b,n, r*32+tt, h]
#pragma unroll
    for (int rep = 0; rep < 4; ++rep) {
        int v = tid + rep * 256;
        int r = v >> 4, h4 = v & 15;
        float4 f = *(const float4*)(src + (size_t)(r * 32 + tt) * H_ + h4 * 4);
        T[r][h4 * 4 + 0] = f.x;
        T[r][h4 * 4 + 1] = f.y;
        T[r][h4 * 4 + 2] = f.z;
        T[r][h4 * 4 + 3] = f.w;
    }
    __syncthreads();
    // out[b, tt*64+h, n*64 + 4*r4 + e] = T[4*r4+e][h] * wsum[...]
#pragma unroll
    for (int rep = 0; rep < 4; ++rep) {
        int v = tid + rep * 256;
        int h = v >> 4, r4 = v & 15;
        float4 w4 = *(const float4*)(wsum + n * 64 + r4 * 4);
        float4 o4 = make_float4(T[r4 * 4 + 0][h] * w4.x, T[r4 * 4 + 1][h] * w4.y,
                                T[r4 * 4 + 2][h] * w4.z, T[r4 * 4 + 3][h] * w4.w);
        *(float4*)(out + ((size_t)(b * S_ + tt * 64 + h) * D_) + n * 64 + r4 * 4) = o4;
    }
}

// ---------------------------------------------------------------------------
extern "C" void kernel_launch(void* const* d_in, const int* in_sizes, int n_in,
                              void* d_out, int out_size, void* d_ws, size_t ws_size,
                              hipStream_t stream) {
    const float* x = (const float*)d_in[0];
    const float* Wqkv = (const float*)d_in[1];
    const float* Wout = (const float*)d_in[2];
    float* out = (float*)d_out;
    float* ws = (float*)d_ws;

    const size_t per = (size_t)B_ * N_ * S_ * H_;  // 4,194,304 floats
    float* wsum = ws;           // 1024
    float* qb_ = ws + 1024;
    float* kb_ = qb_ + per;
    float* vb_ = kb_ + per;
    float* ob_ = vb_ + per;     // total ~67 MB

    k_wsum<<<dim3(64), dim3(256), 0, stream>>>(Wout, wsum);
    k_qkv<<<dim3(32, 3, 32), dim3(256), 0, stream>>>(x, Wqkv, qb_, kb_, vb_);
    k_attn<<<dim3(32, 32), dim3(256), 0, stream>>>(qb_, kb_, vb_, ob_);
    k_perm<<<dim3(32, 16, 2), dim3(256), 0, stream>>>(ob_, wsum, out);
}

// Round 3
// 169.718 us; speedup vs baseline: 8.5959x; 8.5959x over previous
//
#include <hip/hip_runtime.h>
#include <hip/hip_bf16.h>

#define B_ 2
#define S_ 2048
#define D_ 1024
#define N_ 16
#define H_ 64

typedef unsigned short u16;
typedef unsigned int u32;
typedef __bf16 bf16x8 __attribute__((ext_vector_type(8)));
typedef u16 u16x8 __attribute__((ext_vector_type(8)));
typedef float f4v __attribute__((ext_vector_type(4)));

__device__ __forceinline__ u16 f2b(float f) {
    u32 u = __builtin_bit_cast(u32, f);
    u32 r = (u + 0x7FFFu + ((u >> 16) & 1u)) >> 16;
    return (u16)r;
}
__device__ __forceinline__ bf16x8 asbf(u16x8 v) { return __builtin_bit_cast(bf16x8, v); }

// ---------------------------------------------------------------------------
// convert x fp32 -> bf16 [4096][1024]
__global__ __launch_bounds__(256) void k_cvt_x(const float* __restrict__ x,
                                               u16* __restrict__ xb) {
    size_t i = ((size_t)blockIdx.x * 256 + threadIdx.x) * 8;
    float4 f0 = *(const float4*)(x + i);
    float4 f1 = *(const float4*)(x + i + 4);
    u16x8 o;
    o[0] = f2b(f0.x); o[1] = f2b(f0.y); o[2] = f2b(f0.z); o[3] = f2b(f0.w);
    o[4] = f2b(f1.x); o[5] = f2b(f1.y); o[6] = f2b(f1.z); o[7] = f2b(f1.w);
    *(u16x8*)(xb + i) = o;
}

// convert W_qkv fp32 -> bf16, scaling Q columns (j<64) by 0.125
__global__ __launch_bounds__(256) void k_cvt_w(const float* __restrict__ w,
                                               u16* __restrict__ wb) {
    size_t i = ((size_t)blockIdx.x * 256 + threadIdx.x) * 8;
    int g = (int)((i >> 3) % 24);          // 8-col group within 192
    float sc = (g < 8) ? 0.125f : 1.0f;
    float4 f0 = *(const float4*)(w + i);
    float4 f1 = *(const float4*)(w + i + 4);
    u16x8 o;
    o[0] = f2b(f0.x * sc); o[1] = f2b(f0.y * sc); o[2] = f2b(f0.z * sc); o[3] = f2b(f0.w * sc);
    o[4] = f2b(f1.x * sc); o[5] = f2b(f1.y * sc); o[6] = f2b(f1.z * sc); o[7] = f2b(f1.w * sc);
    *(u16x8*)(wb + i) = o;
}

// ---------------------------------------------------------------------------
// wsum[d] = sum over 1024 rows of W_out
__global__ __launch_bounds__(256) void k_wsum(const float* __restrict__ Wout,
                                              float* __restrict__ wsum) {
    __shared__ float red[16][17];
    const int dd = threadIdx.x & 15, rr = threadIdx.x >> 4;
    const int d = blockIdx.x * 16 + dd;
    float s = 0.f;
    for (int r = rr * 64; r < rr * 64 + 64; ++r) s += Wout[(size_t)r * 1024 + d];
    red[rr][dd] = s;
    __syncthreads();
    if (rr == 0) {
        float t = 0.f;
#pragma unroll
        for (int k = 0; k < 16; ++k) t += red[k][dd];
        wsum[d] = t;
    }
}

// ---------------------------------------------------------------------------
// QKV GEMM, MFMA bf16. Tile 128(M) x 192(N) x 64(K-step). 512 thr = 8 waves.
// grid (32 row-tiles over B*S, 16 heads). Outputs q/k/v as bf16 [bn][s][64].
__global__ __launch_bounds__(512) void k_qkv(const u16* __restrict__ xb,
                                             const u16* __restrict__ wb,
                                             u16* __restrict__ qbuf,
                                             u16* __restrict__ kbuf,
                                             u16* __restrict__ vbuf) {
    __shared__ u16 As[128 * 64];   // [row][64k] swizzled
    __shared__ u16 Bst[192 * 64];  // [j][64k] swizzled
    const int st = blockIdx.x, n = blockIdx.y;
    const int t = threadIdx.x;
    const int w = t >> 6, lane = t & 63, hi2 = lane >> 4, lo4 = lane & 15;

    // staging addresses
    const int arow = t >> 2, aq4 = t & 3, ar7 = arow & 7;
    const u16* Ag = xb + (size_t)(st * 128 + arow) * 1024 + aq4 * 16;
    const int bk = t >> 3, bj0 = (t & 7) * 24;
    const u16* Bg = wb + ((size_t)n * 1024 + bk) * 192 + bj0;

    f4v acc[12];
#pragma unroll
    for (int i = 0; i < 12; ++i) acc[i] = (f4v){0.f, 0.f, 0.f, 0.f};

    const int rsw = (lo4 & 7) << 3;
    for (int kk = 0; kk < 16; ++kk) {
        __syncthreads();
        // stage A (32B/thread)
        u16x8 a0 = *(const u16x8*)(Ag + kk * 64);
        u16x8 a1 = *(const u16x8*)(Ag + kk * 64 + 8);
        *(u16x8*)(As + arow * 64 + ((aq4 * 16 + 0) ^ (ar7 << 3))) = a0;
        *(u16x8*)(As + arow * 64 + ((aq4 * 16 + 8) ^ (ar7 << 3))) = a1;
        // stage B transposed (24 cols/thread)
        u16x8 b0 = *(const u16x8*)(Bg + (size_t)kk * 64 * 192);
        u16x8 b1 = *(const u16x8*)(Bg + (size_t)kk * 64 * 192 + 8);
        u16x8 b2 = *(const u16x8*)(Bg + (size_t)kk * 64 * 192 + 16);
#pragma unroll
        for (int e = 0; e < 8; ++e) {
            Bst[(bj0 + e) * 64 + (bk ^ (e << 3))] = b0[e];
            Bst[(bj0 + 8 + e) * 64 + (bk ^ (e << 3))] = b1[e];
            Bst[(bj0 + 16 + e) * 64 + (bk ^ (e << 3))] = b2[e];
        }
        __syncthreads();
        const u16* ar = As + (w * 16 + lo4) * 64;
        bf16x8 fa0 = asbf(*(const u16x8*)(ar + ((hi2 * 8) ^ rsw)));
        bf16x8 fa1 = asbf(*(const u16x8*)(ar + ((hi2 * 8 + 32) ^ rsw)));
#pragma unroll
        for (int fj = 0; fj < 12; ++fj) {
            const u16* br = Bst + (fj * 16 + lo4) * 64;
            bf16x8 fb0 = asbf(*(const u16x8*)(br + ((hi2 * 8) ^ rsw)));
            bf16x8 fb1 = asbf(*(const u16x8*)(br + ((hi2 * 8 + 32) ^ rsw)));
            acc[fj] = __builtin_amdgcn_mfma_f32_16x16x32_bf16(fa0, fb0, acc[fj], 0, 0, 0);
            acc[fj] = __builtin_amdgcn_mfma_f32_16x16x32_bf16(fa1, fb1, acc[fj], 0, 0, 0);
        }
    }
    // epilogue: scalar bf16 stores
#pragma unroll
    for (int fj = 0; fj < 12; ++fj) {
        const int sec = fj >> 2;
        const int h = (fj & 3) * 16 + lo4;
        u16* dst = (sec == 0) ? qbuf : (sec == 1) ? kbuf : vbuf;
#pragma unroll
        for (int r = 0; r < 4; ++r) {
            int rg = st * 128 + w * 16 + hi2 * 4 + r;
            int b = rg >> 11, s = rg & 2047;
            dst[((size_t)(b * 16 + n) * 2048 + s) * 64 + h] = f2b(acc[fj][r]);
        }
    }
}

// ---------------------------------------------------------------------------
// V transpose: vbuf [bn][s][64] -> vt [bn][64][2048]
__global__ __launch_bounds__(256) void k_vt(const u16* __restrict__ vbuf,
                                            u16* __restrict__ vt) {
    const int bn = blockIdx.y;
    const int s = blockIdx.x * 256 + threadIdx.x;
    const u16* src = vbuf + ((size_t)bn * 2048 + s) * 64;
    u16x8 v[8];
#pragma unroll
    for (int i = 0; i < 8; ++i) v[i] = *(const u16x8*)(src + i * 8);
    u16* dst = vt + (size_t)bn * 64 * 2048 + s;
#pragma unroll
    for (int h = 0; h < 64; ++h) dst[(size_t)h * 2048] = v[h >> 3][h & 7];
}

// ---------------------------------------------------------------------------
// MFMA flash attention. Q-block 128 (8 waves x 16 rows), KV-tile 64.
// grid 512 (1D): bn = id&31, qx = id>>5, qb = balance-perm(qx).
__global__ __launch_bounds__(512) void k_attn(const u16* __restrict__ qbuf,
                                              const u16* __restrict__ kbuf,
                                              const u16* __restrict__ vt,
                                              float* __restrict__ obuf) {
    __shared__ u16 Ks[64 * 64];       // [kv][64h] swizzled
    __shared__ u16 Vs[64 * 64];       // [h][64kv] swizzled
    __shared__ u16 Ps[8 * 16 * 64];   // per-wave [16q][64kv] swizzled
    const int id = blockIdx.x;
    const int bn = id & 31;
    const int qx = id >> 5;
    const int qb = (qx < 8) ? (15 - 2 * qx) : (2 * (qx - 8));  // heavy/light pairing
    const int t = threadIdx.x;
    const int w = t >> 6, lane = t & 63, hi2 = lane >> 4, lo4 = lane & 15;

    // Q fragments (held in registers)
    const u16* Qp = qbuf + ((size_t)bn * 2048 + qb * 128 + w * 16 + lo4) * 64;
    bf16x8 aq0 = asbf(*(const u16x8*)(Qp + hi2 * 8));
    bf16x8 aq1 = asbf(*(const u16x8*)(Qp + 32 + hi2 * 8));

    // staging addresses (16B per thread per tile for K and V)
    const int srow = t >> 3, so = t & 7, sr7 = srow & 7;
    const u16* Kg = kbuf + (size_t)bn * 2048 * 64 + (size_t)srow * 64 + so * 8;
    const u16* Vg = vt + (size_t)bn * 64 * 2048 + (size_t)srow * 2048 + so * 8;
    u16* Kl = Ks + srow * 64 + ((so * 8) ^ (sr7 << 3));
    u16* Vl = Vs + srow * 64 + ((so * 8) ^ (sr7 << 3));

    f4v accO[4];
#pragma unroll
    for (int i = 0; i < 4; ++i) accO[i] = (f4v){0.f, 0.f, 0.f, 0.f};
    float m[4], l[4];
#pragma unroll
    for (int r = 0; r < 4; ++r) { m[r] = -3.0e38f; l[r] = 0.f; }

    const int rsw = (lo4 & 7) << 3;
    u16* Pw = Ps + w * 1024;
    const int nkb = 2 * qb + 2;

    for (int kb = 0; kb < nkb; ++kb) {
        __syncthreads();  // previous tile fully consumed
        *(u16x8*)Kl = *(const u16x8*)(Kg + (size_t)kb * 64 * 64);
        *(u16x8*)Vl = *(const u16x8*)(Vg + kb * 64);
        __syncthreads();  // staged tile visible

        // S = Q K^T
        f4v s4[4];
#pragma unroll
        for (int i = 0; i < 4; ++i) s4[i] = (f4v){0.f, 0.f, 0.f, 0.f};
#pragma unroll
        for (int fj = 0; fj < 4; ++fj) {
            const u16* kr = Ks + (fj * 16 + lo4) * 64;
            bf16x8 fb0 = asbf(*(const u16x8*)(kr + ((hi2 * 8) ^ rsw)));
            bf16x8 fb1 = asbf(*(const u16x8*)(kr + ((hi2 * 8 + 32) ^ rsw)));
            s4[fj] = __builtin_amdgcn_mfma_f32_16x16x32_bf16(aq0, fb0, s4[fj], 0, 0, 0);
            s4[fj] = __builtin_amdgcn_mfma_f32_16x16x32_bf16(aq1, fb1, s4[fj], 0, 0, 0);
        }
        // causal mask (only diagonal-straddling tiles)
        if (kb >= 2 * qb) {
#pragma unroll
            for (int fi = 0; fi < 4; ++fi)
#pragma unroll
                for (int r = 0; r < 4; ++r) {
                    int kvg = kb * 64 + fi * 16 + lo4;
                    int qg = qb * 128 + w * 16 + hi2 * 4 + r;
                    if (kvg > qg) s4[fi][r] = -3.0e38f;
                }
        }
        // online softmax (rows live on 16-lane groups)
#pragma unroll
        for (int r = 0; r < 4; ++r) {
            float tm = fmaxf(fmaxf(s4[0][r], s4[1][r]), fmaxf(s4[2][r], s4[3][r]));
            tm = fmaxf(tm, __shfl_xor(tm, 1));
            tm = fmaxf(tm, __shfl_xor(tm, 2));
            tm = fmaxf(tm, __shfl_xor(tm, 4));
            tm = fmaxf(tm, __shfl_xor(tm, 8));
            float mn = fmaxf(m[r], tm);
            float fs = __expf(m[r] - mn);
            m[r] = mn;
            float ts = 0.f;
            const int prow = hi2 * 4 + r;
            const int psw = (prow & 7) << 3;
#pragma unroll
            for (int fi = 0; fi < 4; ++fi) {
                float p = __expf(s4[fi][r] - mn);
                ts += p;
                Pw[prow * 64 + ((fi * 16 + lo4) ^ psw)] = f2b(p);
            }
            ts += __shfl_xor(ts, 1);
            ts += __shfl_xor(ts, 2);
            ts += __shfl_xor(ts, 4);
            ts += __shfl_xor(ts, 8);
            l[r] = l[r] * fs + ts;
#pragma unroll
            for (int fh = 0; fh < 4; ++fh) accO[fh][r] *= fs;
        }
        // O += P V   (P from wave-private LDS, V from shared tile)
        const u16* pr = Pw + lo4 * 64;
        bf16x8 ap0 = asbf(*(const u16x8*)(pr + ((hi2 * 8) ^ rsw)));
        bf16x8 ap1 = asbf(*(const u16x8*)(pr + ((hi2 * 8 + 32) ^ rsw)));
#pragma unroll
        for (int fh = 0; fh < 4; ++fh) {
            const u16* vr = Vs + (fh * 16 + lo4) * 64;
            bf16x8 fb0 = asbf(*(const u16x8*)(vr + ((hi2 * 8) ^ rsw)));
            bf16x8 fb1 = asbf(*(const u16x8*)(vr + ((hi2 * 8 + 32) ^ rsw)));
            accO[fh] = __builtin_amdgcn_mfma_f32_16x16x32_bf16(ap0, fb0, accO[fh], 0, 0, 0);
            accO[fh] = __builtin_amdgcn_mfma_f32_16x16x32_bf16(ap1, fb1, accO[fh], 0, 0, 0);
        }
    }
    // normalize + store fp32
#pragma unroll
    for (int r = 0; r < 4; ++r) {
        float inv = 1.f / l[r];
        size_t row = (size_t)bn * 2048 + qb * 128 + w * 16 + hi2 * 4 + r;
#pragma unroll
        for (int fh = 0; fh < 4; ++fh)
            obuf[row * 64 + fh * 16 + lo4] = accO[fh][r] * inv;
    }
}

// ---------------------------------------------------------------------------
// K4: permute + scale. final[b,s2,64n+r] = attn[b,n, 32r+s2/64, s2%64] * wsum[64n+r]
__global__ __launch_bounds__(256) void k_perm(const float* __restrict__ obuf,
                                              const float* __restrict__ wsum,
                                              float* __restrict__ out) {
    __shared__ float T[64][65];
    const int tt = blockIdx.x, n = blockIdx.y, b = blockIdx.z;
    const int tid = threadIdx.x;
    const float* src = obuf + ((size_t)(b * 16 + n) * S_) * H_;
#pragma unroll
    for (int rep = 0; rep < 4; ++rep) {
        int v = tid + rep * 256;
        int r = v >> 4, h4 = v & 15;
        float4 f = *(const float4*)(src + (size_t)(r * 32 + tt) * H_ + h4 * 4);
        T[r][h4 * 4 + 0] = f.x;
        T[r][h4 * 4 + 1] = f.y;
        T[r][h4 * 4 + 2] = f.z;
        T[r][h4 * 4 + 3] = f.w;
    }
    __syncthreads();
#pragma unroll
    for (int rep = 0; rep < 4; ++rep) {
        int v = tid + rep * 256;
        int h = v >> 4, r4 = v & 15;
        float4 w4 = *(const float4*)(wsum + n * 64 + r4 * 4);
        float4 o4 = make_float4(T[r4 * 4 + 0][h] * w4.x, T[r4 * 4 + 1][h] * w4.y,
                                T[r4 * 4 + 2][h] * w4.z, T[r4 * 4 + 3][h] * w4.w);
        *(float4*)(out + ((size_t)(b * S_ + tt * 64 + h) * D_) + n * 64 + r4 * 4) = o4;
    }
}

// ---------------------------------------------------------------------------
extern "C" void kernel_launch(void* const* d_in, const int* in_sizes, int n_in,
                              void* d_out, int out_size, void* d_ws, size_t ws_size,
                              hipStream_t stream) {
    const float* x = (const float*)d_in[0];
    const float* Wqkv = (const float*)d_in[1];
    const float* Wout = (const float*)d_in[2];
    float* out = (float*)d_out;

    char* p = (char*)d_ws;
    float* wsum = (float*)p; p += 4096;
    u16* xb = (u16*)p; p += (size_t)4096 * 1024 * 2;          // 8 MB
    u16* wb = (u16*)p; p += (size_t)16 * 1024 * 192 * 2;      // 6 MB
    u16* qb_ = (u16*)p; p += (size_t)32 * 2048 * 64 * 2;      // 8 MB
    u16* kb_ = (u16*)p; p += (size_t)32 * 2048 * 64 * 2;      // 8 MB
    u16* vb_ = (u16*)p; p += (size_t)32 * 2048 * 64 * 2;      // 8 MB
    u16* vt_ = (u16*)p; p += (size_t)32 * 2048 * 64 * 2;      // 8 MB
    float* ob_ = (float*)p;                                   // 16 MB

    k_cvt_x<<<2048, 256, 0, stream>>>(x, xb);
    k_cvt_w<<<1536, 256, 0, stream>>>(Wqkv, wb);
    k_wsum<<<64, 256, 0, stream>>>(Wout, wsum);
    k_qkv<<<dim3(32, 16), 512, 0, stream>>>(xb, wb, qb_, kb_, vb_);
    k_vt<<<dim3(8, 32), 256, 0, stream>>>(vb_, vt_);
    k_attn<<<512, 512, 0, stream>>>(qb_, kb_, vt_, ob_);
    k_perm<<<dim3(32, 16, 2), 256, 0, stream>>>(ob_, wsum, out);
}

// Round 4
// 101.002 us; speedup vs baseline: 14.4441x; 1.6803x over previous
//
#include <hip/hip_runtime.h>
#include <hip/hip_bf16.h>

#define B_ 2
#define S_ 2048
#define D_ 1024
#define N_ 16
#define H_ 64

typedef unsigned short u16;
typedef unsigned int u32;
typedef __bf16 bf16x8 __attribute__((ext_vector_type(8)));
typedef u16 u16x8 __attribute__((ext_vector_type(8)));
typedef u32 u32x2 __attribute__((ext_vector_type(2)));
typedef float f4v __attribute__((ext_vector_type(4)));

__device__ __forceinline__ u16 f2b(float f) {
    u32 u = __builtin_bit_cast(u32, f);
    u32 r = (u + 0x7FFFu + ((u >> 16) & 1u)) >> 16;
    return (u16)r;
}
__device__ __forceinline__ bf16x8 asbf(u16x8 v) { return __builtin_bit_cast(bf16x8, v); }
__device__ __forceinline__ u32 cvtpk(float a, float b) {
    u32 r;
    asm("v_cvt_pk_bf16_f32 %0, %1, %2" : "=v"(r) : "v"(a), "v"(b));
    return r;
}

// ---------------------------------------------------------------------------
// convert x fp32 -> bf16 [4096][1024]
__global__ __launch_bounds__(256) void k_cvt_x(const float* __restrict__ x,
                                               u16* __restrict__ xb) {
    size_t i = ((size_t)blockIdx.x * 256 + threadIdx.x) * 8;
    float4 f0 = *(const float4*)(x + i);
    float4 f1 = *(const float4*)(x + i + 4);
    u16x8 o;
    o[0] = f2b(f0.x); o[1] = f2b(f0.y); o[2] = f2b(f0.z); o[3] = f2b(f0.w);
    o[4] = f2b(f1.x); o[5] = f2b(f1.y); o[6] = f2b(f1.z); o[7] = f2b(f1.w);
    *(u16x8*)(xb + i) = o;
}

// ---------------------------------------------------------------------------
// W_qkv fp32 [n][1024 d][192 j] -> bf16 TRANSPOSED wt [n][192 j][1024 d],
// Q columns (j<64) scaled by 0.125.  LDS 64x64 transpose tiles.
__global__ __launch_bounds__(256) void k_cvt_w(const float* __restrict__ w,
                                               u16* __restrict__ wt) {
    __shared__ float T[64][65];
    const int d0 = blockIdx.x * 64, jt = blockIdx.y, n = blockIdx.z;
    const int j0 = jt * 64;
    const float sc = (jt == 0) ? 0.125f : 1.0f;
    const int t = threadIdx.x;
#pragma unroll
    for (int rep = 0; rep < 4; ++rep) {
        int v = t + rep * 256;
        int row = v >> 4, c4 = v & 15;
        float4 f = *(const float4*)(w + ((size_t)(n * 1024 + d0 + row)) * 192 + j0 + c4 * 4);
        T[row][c4 * 4 + 0] = f.x * sc;
        T[row][c4 * 4 + 1] = f.y * sc;
        T[row][c4 * 4 + 2] = f.z * sc;
        T[row][c4 * 4 + 3] = f.w * sc;
    }
    __syncthreads();
#pragma unroll
    for (int rep = 0; rep < 2; ++rep) {
        int c = t + rep * 256;
        int j = c >> 3, db = c & 7;
        u16x8 o;
#pragma unroll
        for (int e = 0; e < 8; ++e) o[e] = f2b(T[db * 8 + e][j]);
        *(u16x8*)(wt + ((size_t)(n * 192 + j0 + j)) * 1024 + d0 + db * 8) = o;
    }
}

// ---------------------------------------------------------------------------
// wsum[d] = sum over 1024 rows of W_out
__global__ __launch_bounds__(256) void k_wsum(const float* __restrict__ Wout,
                                              float* __restrict__ wsum) {
    __shared__ float red[16][17];
    const int dd = threadIdx.x & 15, rr = threadIdx.x >> 4;
    const int d = blockIdx.x * 16 + dd;
    float s = 0.f;
    for (int r = rr * 64; r < rr * 64 + 64; ++r) s += Wout[(size_t)r * 1024 + d];
    red[rr][dd] = s;
    __syncthreads();
    if (rr == 0) {
        float t = 0.f;
#pragma unroll
        for (int k = 0; k < 16; ++k) t += red[k][dd];
        wsum[d] = t;
    }
}

// ---------------------------------------------------------------------------
// QKV GEMM, MFMA bf16. Tile 128(M) x 192(N) x 64(K-step). 512 thr = 8 waves.
// B from pre-transposed wt. Prefetch (T14). LDS-bounce epilogue; V stored
// transposed directly to vt[bn][h][s].
__global__ __launch_bounds__(512) void k_qkv(const u16* __restrict__ xb,
                                             const u16* __restrict__ wt,
                                             u16* __restrict__ qbuf,
                                             u16* __restrict__ kbuf,
                                             u16* __restrict__ vt) {
    __shared__ u16 As[128 * 64];   // [row][64k] swizzled
    __shared__ u16 Bst[192 * 64];  // [j][64k]  swizzled
    const int st = blockIdx.x, n = blockIdx.y;
    const int t = threadIdx.x;
    const int w = t >> 6, lane = t & 63, hi2 = lane >> 4, lo4 = lane & 15;

    // A staging: thread covers row arow, k-slice aq4*16..+15 (2 x u16x8)
    const int arow = t >> 2, aq4 = t & 3, ar7 = arow & 7;
    const u16* Ag = xb + (size_t)(st * 128 + arow) * 1024 + aq4 * 16;
    u16* Al0 = As + arow * 64 + ((aq4 * 16 + 0) ^ (ar7 << 3));
    u16* Al1 = As + arow * 64 + ((aq4 * 16 + 8) ^ (ar7 << 3));
    // B staging: rows br0, br0+64, br0+128; k-slice boff*8 (3 x u16x8)
    const int br0 = t >> 3, boff = t & 7;
    const u16* Bg0 = wt + (size_t)(n * 192 + br0) * 1024 + boff * 8;
    const u16* Bg1 = Bg0 + (size_t)64 * 1024;
    const u16* Bg2 = Bg0 + (size_t)128 * 1024;
    const int bsw = (boff * 8) ^ ((br0 & 7) << 3);
    u16* Bl0 = Bst + (br0 + 0) * 64 + bsw;
    u16* Bl1 = Bst + (br0 + 64) * 64 + bsw;
    u16* Bl2 = Bst + (br0 + 128) * 64 + bsw;

    f4v acc[12];
#pragma unroll
    for (int i = 0; i < 12; ++i) acc[i] = (f4v){0.f, 0.f, 0.f, 0.f};

    const int rsw = (lo4 & 7) << 3;
    u16x8 ra0 = *(const u16x8*)(Ag);
    u16x8 ra1 = *(const u16x8*)(Ag + 8);
    u16x8 rb0 = *(const u16x8*)(Bg0);
    u16x8 rb1 = *(const u16x8*)(Bg1);
    u16x8 rb2 = *(const u16x8*)(Bg2);

    for (int kk = 0; kk < 16; ++kk) {
        __syncthreads();
        *(u16x8*)Al0 = ra0;
        *(u16x8*)Al1 = ra1;
        *(u16x8*)Bl0 = rb0;
        *(u16x8*)Bl1 = rb1;
        *(u16x8*)Bl2 = rb2;
        if (kk < 15) {
            int o = (kk + 1) * 64;
            ra0 = *(const u16x8*)(Ag + o);
            ra1 = *(const u16x8*)(Ag + o + 8);
            rb0 = *(const u16x8*)(Bg0 + o);
            rb1 = *(const u16x8*)(Bg1 + o);
            rb2 = *(const u16x8*)(Bg2 + o);
        }
        __syncthreads();
        const u16* ar = As + (w * 16 + lo4) * 64;
        bf16x8 fa0 = asbf(*(const u16x8*)(ar + ((hi2 * 8) ^ rsw)));
        bf16x8 fa1 = asbf(*(const u16x8*)(ar + ((hi2 * 8 + 32) ^ rsw)));
        __builtin_amdgcn_s_setprio(1);
#pragma unroll
        for (int fj = 0; fj < 12; ++fj) {
            const u16* br = Bst + (fj * 16 + lo4) * 64;
            bf16x8 fb0 = asbf(*(const u16x8*)(br + ((hi2 * 8) ^ rsw)));
            bf16x8 fb1 = asbf(*(const u16x8*)(br + ((hi2 * 8 + 32) ^ rsw)));
            acc[fj] = __builtin_amdgcn_mfma_f32_16x16x32_bf16(fa0, fb0, acc[fj], 0, 0, 0);
            acc[fj] = __builtin_amdgcn_mfma_f32_16x16x32_bf16(fa1, fb1, acc[fj], 0, 0, 0);
        }
        __builtin_amdgcn_s_setprio(0);
    }

    // epilogue: LDS bounce per section for vectorized global stores
    const int b = st >> 4, s128 = (st & 15) * 128;
    u16* Cs = As;  // 16KB reuse
#pragma unroll
    for (int sec = 0; sec < 3; ++sec) {
        __syncthreads();
#pragma unroll
        for (int q4 = 0; q4 < 4; ++q4)
#pragma unroll
            for (int r = 0; r < 4; ++r)
                Cs[(w * 16 + hi2 * 4 + r) * 64 + q4 * 16 + lo4] = f2b(acc[sec * 4 + q4][r]);
        __syncthreads();
        if (sec == 2) {
            // V: transpose to vt[bn][h][s]
            const int h = t & 63, sb = t >> 6;
            u16x8 o0, o1;
#pragma unroll
            for (int e = 0; e < 8; ++e) o0[e] = Cs[(sb * 16 + e) * 64 + h];
#pragma unroll
            for (int e = 0; e < 8; ++e) o1[e] = Cs[(sb * 16 + 8 + e) * 64 + h];
            u16* dst = vt + ((size_t)(b * 16 + n) * 64 + h) * 2048 + s128 + sb * 16;
            *(u16x8*)dst = o0;
            *(u16x8*)(dst + 8) = o1;
        } else {
            const int row = t >> 2, off = (t & 3) * 16;
            u16* dst = (sec == 0) ? qbuf : kbuf;
            dst += ((size_t)(b * 16 + n) * 2048 + s128 + row) * 64 + off;
            *(u16x8*)dst = *(const u16x8*)(Cs + row * 64 + off);
            *(u16x8*)(dst + 8) = *(const u16x8*)(Cs + row * 64 + off + 8);
        }
    }
}

// ---------------------------------------------------------------------------
// MFMA flash attention, swapped-operand form. QBLK=128 (8 waves x 16 q-cols),
// KVBLK=64. Per-lane-local softmax; P via cvt_pk into wave-private swizzled
// LDS; PV computes O^T = V^T * P^T. T14 prefetch; LPT schedule per XCD.
__global__ __launch_bounds__(512) void k_attn(const u16* __restrict__ qbuf,
                                              const u16* __restrict__ kbuf,
                                              const u16* __restrict__ vt,
                                              float* __restrict__ obuf) {
    __shared__ u16 Ks[64 * 64];      // [kv][64h] swizzled
    __shared__ u16 Vs[64 * 64];      // [h][64kv] swizzled
    __shared__ u16 Ps[8 * 16 * 64];  // per-wave [16q][64kv] swizzled
    const int p = blockIdx.x;
    const int j = p >> 3;
    const int bn = (p & 7) * 4 + (j & 3);   // 4 bn per XCD: KV L2-resident
    const int qb = 15 - (j >> 2);           // LPT: heavy q-tiles first
    const int t = threadIdx.x;
    const int w = t >> 6, lane = t & 63, hi2 = lane >> 4, lo4 = lane & 15;

    // Q as B-operand fragments (col = q = lo4, k = h = hi2*8+e)
    const int q = qb * 128 + w * 16 + lo4;
    const u16* Qp = qbuf + ((size_t)bn * 2048 + q) * 64;
    bf16x8 bq0 = asbf(*(const u16x8*)(Qp + hi2 * 8));
    bf16x8 bq1 = asbf(*(const u16x8*)(Qp + 32 + hi2 * 8));

    // staging (16B/thread for K and V per tile)
    const int srow = t >> 3, so = t & 7;
    const u16* Kg = kbuf + (size_t)bn * 2048 * 64 + (size_t)srow * 64 + so * 8;
    const u16* Vg = vt + (size_t)bn * 64 * 2048 + (size_t)srow * 2048 + so * 8;
    u16* Kl = Ks + srow * 64 + ((so * 8) ^ ((srow & 7) << 3));
    u16* Vl = Vs + srow * 64 + ((so * 8) ^ ((srow & 7) << 3));

    f4v accO[4];
#pragma unroll
    for (int i = 0; i < 4; ++i) accO[i] = (f4v){0.f, 0.f, 0.f, 0.f};
    float m = -3.0e38f, l = 0.f;

    const int rsw = (lo4 & 7) << 3;
    u16* Pw = Ps + w * 1024 + lo4 * 64;  // this lane's q-row
    const int nkb = 2 * qb + 2;

    u16x8 kreg = *(const u16x8*)(Kg);
    u16x8 vreg = *(const u16x8*)(Vg);

    for (int kb = 0; kb < nkb; ++kb) {
        __syncthreads();  // previous tile fully consumed
        *(u16x8*)Kl = kreg;
        *(u16x8*)Vl = vreg;
        if (kb + 1 < nkb) {
            kreg = *(const u16x8*)(Kg + (size_t)(kb + 1) * 4096);
            vreg = *(const u16x8*)(Vg + (kb + 1) * 64);
        }
        __syncthreads();  // staged tile visible

        // S^T = K Q : D[kv][q] with kv = fi*16 + hi2*4 + r, q = lane-local
        f4v s4[4];
#pragma unroll
        for (int i = 0; i < 4; ++i) s4[i] = (f4v){0.f, 0.f, 0.f, 0.f};
        __builtin_amdgcn_s_setprio(1);
#pragma unroll
        for (int fi = 0; fi < 4; ++fi) {
            const u16* kr = Ks + (fi * 16 + lo4) * 64;
            bf16x8 ka0 = asbf(*(const u16x8*)(kr + ((hi2 * 8) ^ rsw)));
            bf16x8 ka1 = asbf(*(const u16x8*)(kr + ((hi2 * 8 + 32) ^ rsw)));
            s4[fi] = __builtin_amdgcn_mfma_f32_16x16x32_bf16(ka0, bq0, s4[fi], 0, 0, 0);
            s4[fi] = __builtin_amdgcn_mfma_f32_16x16x32_bf16(ka1, bq1, s4[fi], 0, 0, 0);
        }
        __builtin_amdgcn_s_setprio(0);

        // causal mask (diagonal-straddling tiles only)
        if (kb >= 2 * qb) {
#pragma unroll
            for (int fi = 0; fi < 4; ++fi)
#pragma unroll
                for (int r = 0; r < 4; ++r) {
                    int kvg = kb * 64 + fi * 16 + hi2 * 4 + r;
                    if (kvg > q) s4[fi][r] = -3.0e38f;
                }
        }

        // per-lane softmax over 16 local kv values (+2 shfl across hi2)
        float pm = s4[0][0];
#pragma unroll
        for (int fi = 0; fi < 4; ++fi)
#pragma unroll
            for (int r = 0; r < 4; ++r) pm = fmaxf(pm, s4[fi][r]);
        pm = fmaxf(pm, __shfl_xor(pm, 16));
        pm = fmaxf(pm, __shfl_xor(pm, 32));
        float mn = fmaxf(m, pm);
        float fs = __expf(m - mn);
        m = mn;
        float ts = 0.f;
#pragma unroll
        for (int fi = 0; fi < 4; ++fi) {
#pragma unroll
            for (int r = 0; r < 4; ++r) {
                float pv = __expf(s4[fi][r] - mn);
                s4[fi][r] = pv;
                ts += pv;
            }
            u32x2 pk;
            pk[0] = cvtpk(s4[fi][0], s4[fi][1]);
            pk[1] = cvtpk(s4[fi][2], s4[fi][3]);
            *(u32x2*)(Pw + ((fi * 16 + hi2 * 4) ^ rsw)) = pk;
        }
        ts += __shfl_xor(ts, 16);
        ts += __shfl_xor(ts, 32);
        l = l * fs + ts;
#pragma unroll
        for (int fh = 0; fh < 4; ++fh)
#pragma unroll
            for (int r = 0; r < 4; ++r) accO[fh][r] *= fs;

        // O^T += V^T P^T
        bf16x8 pb0 = asbf(*(const u16x8*)(Pw + ((hi2 * 8) ^ rsw)));
        bf16x8 pb1 = asbf(*(const u16x8*)(Pw + ((32 + hi2 * 8) ^ rsw)));
        __builtin_amdgcn_s_setprio(1);
#pragma unroll
        for (int fh = 0; fh < 4; ++fh) {
            const u16* vr = Vs + (fh * 16 + lo4) * 64;
            bf16x8 va0 = asbf(*(const u16x8*)(vr + ((hi2 * 8) ^ rsw)));
            bf16x8 va1 = asbf(*(const u16x8*)(vr + ((hi2 * 8 + 32) ^ rsw)));
            accO[fh] = __builtin_amdgcn_mfma_f32_16x16x32_bf16(va0, pb0, accO[fh], 0, 0, 0);
            accO[fh] = __builtin_amdgcn_mfma_f32_16x16x32_bf16(va1, pb1, accO[fh], 0, 0, 0);
        }
        __builtin_amdgcn_s_setprio(0);
    }

    // normalize + store fp32 [s][h]
    float inv = 1.f / l;
    float* orow = obuf + ((size_t)bn * 2048 + q) * 64;
#pragma unroll
    for (int fh = 0; fh < 4; ++fh)
#pragma unroll
        for (int r = 0; r < 4; ++r)
            orow[fh * 16 + hi2 * 4 + r] = accO[fh][r] * inv;
}

// ---------------------------------------------------------------------------
// K4: permute + scale. final[b,s2,64n+rr] = attn[b,n, 32rr+s2/64, s2%64] * wsum[64n+rr]
__global__ __launch_bounds__(256) void k_perm(const float* __restrict__ obuf,
                                              const float* __restrict__ wsum,
                                              float* __restrict__ out) {
    __shared__ float T[64][65];
    const int tt = blockIdx.x, n = blockIdx.y, b = blockIdx.z;
    const int tid = threadIdx.x;
    const float* src = obuf + ((size_t)(b * 16 + n) * S_) * H_;
#pragma unroll
    for (int rep = 0; rep < 4; ++rep) {
        int v = tid + rep * 256;
        int r = v >> 4, h4 = v & 15;
        float4 f = *(const float4*)(src + (size_t)(r * 32 + tt) * H_ + h4 * 4);
        T[r][h4 * 4 + 0] = f.x;
        T[r][h4 * 4 + 1] = f.y;
        T[r][h4 * 4 + 2] = f.z;
        T[r][h4 * 4 + 3] = f.w;
    }
    __syncthreads();
#pragma unroll
    for (int rep = 0; rep < 4; ++rep) {
        int v = tid + rep * 256;
        int h = v >> 4, r4 = v & 15;
        float4 w4 = *(const float4*)(wsum + n * 64 + r4 * 4);
        float4 o4 = make_float4(T[r4 * 4 + 0][h] * w4.x, T[r4 * 4 + 1][h] * w4.y,
                                T[r4 * 4 + 2][h] * w4.z, T[r4 * 4 + 3][h] * w4.w);
        *(float4*)(out + ((size_t)(b * S_ + tt * 64 + h) * D_) + n * 64 + r4 * 4) = o4;
    }
}

// ---------------------------------------------------------------------------
extern "C" void kernel_launch(void* const* d_in, const int* in_sizes, int n_in,
                              void* d_out, int out_size, void* d_ws, size_t ws_size,
                              hipStream_t stream) {
    const float* x = (const float*)d_in[0];
    const float* Wqkv = (const float*)d_in[1];
    const float* Wout = (const float*)d_in[2];
    float* out = (float*)d_out;

    char* p = (char*)d_ws;
    float* wsum = (float*)p; p += 4096;
    u16* xb = (u16*)p; p += (size_t)4096 * 1024 * 2;          // 8 MB
    u16* wt = (u16*)p; p += (size_t)16 * 192 * 1024 * 2;      // 6 MB
    u16* qb_ = (u16*)p; p += (size_t)32 * 2048 * 64 * 2;      // 8 MB
    u16* kb_ = (u16*)p; p += (size_t)32 * 2048 * 64 * 2;      // 8 MB
    u16* vt_ = (u16*)p; p += (size_t)32 * 2048 * 64 * 2;      // 8 MB
    float* ob_ = (float*)p;                                   // 16 MB

    k_cvt_x<<<2048, 256, 0, stream>>>(x, xb);
    k_cvt_w<<<dim3(16, 3, 16), 256, 0, stream>>>(Wqkv, wt);
    k_wsum<<<64, 256, 0, stream>>>(Wout, wsum);
    k_qkv<<<dim3(32, 16), 512, 0, stream>>>(xb, wt, qb_, kb_, vt_);
    k_attn<<<512, 512, 0, stream>>>(qb_, kb_, vt_, ob_);
    k_perm<<<dim3(32, 16, 2), 256, 0, stream>>>(ob_, wsum, out);
}